// Round 10
// baseline (144.959 us; speedup 1.0000x reference)
//
#include <hip/hip_runtime.h>

// LocalGLMnet fused forward, v7.
// v6 result: 59.5 us, VGPR=40, occupancy 52%, VALUBusy 35%, no spills.
// Occupancy 2x'd but dur flat -> throughput-bound per CU, not wave-starved.
// Largest per-CU pipe: LDS (50 waves x 100 weight reads ~ 22 us) and general
// instruction count per output. v7: NB=4 batches/thread halves per-output
// LDS+VMEM instructions. Addressing: batches A,B via 10 shared 32-bit
// voffsets off xg; C,D reuse the SAME voffsets off xg2 = xg + 2000 (second
// SGPR base, since 8000B batch stride exceeds the 13-bit load immediate).
// Penalty accumulates raw sum(itm^2), scaled 0.01 once at store.

#define L2E 1.44269504088896340736f

__device__ __forceinline__ float fast_sigmoid(float s) {
    float e = __builtin_amdgcn_exp2f(s * (-L2E));   // exp(-s)
    return __builtin_amdgcn_rcpf(1.0f + e);         // 1/(1+exp(-s))
}

// ---- named-scalar macro machinery (nothing runtime-indexable) ----
// R*100 element offset folds into the 13-bit byte immediate (R*400 <= 3600).
#define P_LOAD_(P, R) \
    xA0##P = xg [oA0 + (R)*100u]; xA1##P = xg [oA1 + (R)*100u]; \
    xA2##P = xg [oA2 + (R)*100u]; xA3##P = xg [oA3 + (R)*100u]; \
    xA4##P = xg [oA4 + (R)*100u]; \
    xB0##P = xg [oB0 + (R)*100u]; xB1##P = xg [oB1 + (R)*100u]; \
    xB2##P = xg [oB2 + (R)*100u]; xB3##P = xg [oB3 + (R)*100u]; \
    xB4##P = xg [oB4 + (R)*100u]; \
    xC0##P = xg2[oA0 + (R)*100u]; xC1##P = xg2[oA1 + (R)*100u]; \
    xC2##P = xg2[oA2 + (R)*100u]; xC3##P = xg2[oA3 + (R)*100u]; \
    xC4##P = xg2[oA4 + (R)*100u]; \
    xD0##P = xg2[oB0 + (R)*100u]; xD1##P = xg2[oB1 + (R)*100u]; \
    xD2##P = xg2[oB2 + (R)*100u]; xD3##P = xg2[oB3 + (R)*100u]; \
    xD4##P = xg2[oB4 + (R)*100u];
#define P_LOAD(P, R) P_LOAD_(P, R)

#define G_TAP_(P, DI, I) { \
    const float4 w4_ = W4p[(I)*125 + (DI)]; \
    const float  we_ = W1p[(I)*125 + (DI)]; \
    sA##I = fmaf(xA4##P, we_, fmaf(xA3##P, w4_.w, fmaf(xA2##P, w4_.z, \
            fmaf(xA1##P, w4_.y, fmaf(xA0##P, w4_.x, sA##I))))); \
    sB##I = fmaf(xB4##P, we_, fmaf(xB3##P, w4_.w, fmaf(xB2##P, w4_.z, \
            fmaf(xB1##P, w4_.y, fmaf(xB0##P, w4_.x, sB##I))))); \
    sC##I = fmaf(xC4##P, we_, fmaf(xC3##P, w4_.w, fmaf(xC2##P, w4_.z, \
            fmaf(xC1##P, w4_.y, fmaf(xC0##P, w4_.x, sC##I))))); \
    sD##I = fmaf(xD4##P, we_, fmaf(xD3##P, w4_.w, fmaf(xD2##P, w4_.z, \
            fmaf(xD1##P, w4_.y, fmaf(xD0##P, w4_.x, sD##I))))); }
#define G_TAP(P, DI, I) G_TAP_(P, DI, I)

// pen accumulates raw itm^2; scaled by 0.01 at store.
#define G_FIN_(I, CA, CB, CC, CD) { \
    float tA_ = fast_sigmoid(sA##I); fA = fmaf(CA, tA_, fA); pA = fmaf(tA_, tA_, pA); \
    float tB_ = fast_sigmoid(sB##I); fB = fmaf(CB, tB_, fB); pB = fmaf(tB_, tB_, pB); \
    float tC_ = fast_sigmoid(sC##I); fC = fmaf(CC, tC_, fC); pC = fmaf(tC_, tC_, pC); \
    float tD_ = fast_sigmoid(sD##I); fD = fmaf(CD, tD_, fD); pD = fmaf(tD_, tD_, pD); }
#define G_FIN(I) G_FIN_(I, cen2A, cen2B, cen2C, cen2D)

#define G_SH_(P) \
    cen2A = cen1A; cen1A = xA2##P; cen2B = cen1B; cen1B = xB2##P; \
    cen2C = cen1C; cen1C = xC2##P; cen2D = cen1D; cen1D = xD2##P;
#define G_SH(P) G_SH_(P)

__global__ __launch_bounds__(256, 4)
void glm_fused(const float* __restrict__ x, const float* __restrict__ w,
               float* __restrict__ out) {
    // weight quarter-tile, split layout: idx = i*125 + jl*5 + di
    __shared__ float4 W4s[1250];   // taps c=0..3   (20 KB, 16B-aligned)
    __shared__ float  W1s[1250];   // tap  c=4      ( 5 KB)

    const int tid   = threadIdx.x;
    const int q     = blockIdx.x & 3;        // j-quarter: j in [q*25, q*25+25)
    const int jbase = q * 25;

    // ---- stage weights once, zeroing out-of-range columns (pad semantics)
    for (int e = tid; e < 1250; e += 256) {
        int i   = e / 125;
        int r   = e - i * 125;
        int jls = r / 5;
        int di  = r - jls * 5;
        int js  = jbase + jls;
        const float* wp = w + i * 2500 + js * 25 + di * 5;
        float w0 = (js >= 2) ? wp[0] : 0.f;
        float w1 = (js >= 1) ? wp[1] : 0.f;
        float w2 = wp[2];
        float w3 = (js <= 98) ? wp[3] : 0.f;
        float w4 = (js <= 97) ? wp[4] : 0.f;
        W4s[e] = make_float4(w0, w1, w2, w3);
        W1s[e] = w4;
    }
    __syncthreads();

    const int t  = (blockIdx.x >> 2) * 256 + tid;
    const int jl = t % 25;
    const int bg = t / 25;                   // group of NB=4 batches (0..4095)
    const int j  = jbase + jl;

    const float4* W4p = W4s + jl * 5;        // + I*125 + DI (imm-foldable)
    const float*  W1p = W1s + jl * 5;

    // two SGPR bases, shared 32-bit voffsets; edge safety via zeroed weights
    const float* __restrict__ xg  = x;
    const float* __restrict__ xg2 = x + 2000;          // batches C,D base
    const unsigned c0 = (j >= 2) ? (unsigned)(j - 2) : 0u;
    const unsigned c1 = (j >= 1) ? (unsigned)(j - 1) : 0u;
    const unsigned c2 = (unsigned)j;
    const unsigned c3 = (j <= 98) ? (unsigned)(j + 1) : 99u;
    const unsigned c4 = (j <= 97) ? (unsigned)(j + 2) : 99u;
    const unsigned bb  = (unsigned)bg * 4000u;         // batch A element base
    const unsigned oA0 = bb + c0, oA1 = bb + c1, oA2 = bb + c2, oA3 = bb + c3, oA4 = bb + c4;
    const unsigned oB0 = oA0 + 1000u, oB1 = oA1 + 1000u, oB2 = oA2 + 1000u,
                   oB3 = oA3 + 1000u, oB4 = oA4 + 1000u;

    float sA0=0.f,sA1=0.f,sA2=0.f,sA3=0.f,sA4=0.f,sA5=0.f,sA6=0.f,sA7=0.f,sA8=0.f,sA9=0.f;
    float sB0=0.f,sB1=0.f,sB2=0.f,sB3=0.f,sB4=0.f,sB5=0.f,sB6=0.f,sB7=0.f,sB8=0.f,sB9=0.f;
    float sC0=0.f,sC1=0.f,sC2=0.f,sC3=0.f,sC4=0.f,sC5=0.f,sC6=0.f,sC7=0.f,sC8=0.f,sC9=0.f;
    float sD0=0.f,sD1=0.f,sD2=0.f,sD3=0.f,sD4=0.f,sD5=0.f,sD6=0.f,sD7=0.f,sD8=0.f,sD9=0.f;
    float fA=0.f,pA=0.f,fB=0.f,pB=0.f,fC=0.f,pC=0.f,fD=0.f,pD=0.f;
    float cen1A=0.f,cen2A=0.f,cen1B=0.f,cen2B=0.f;
    float cen1C=0.f,cen2C=0.f,cen1D=0.f,cen2D=0.f;
    float xA0E,xA1E,xA2E,xA3E,xA4E,xB0E,xB1E,xB2E,xB3E,xB4E;
    float xC0E,xC1E,xC2E,xC3E,xC4E,xD0E,xD1E,xD2E,xD3E,xD4E;
    float xA0O,xA1O,xA2O,xA3O,xA4O,xB0O,xB1O,xB2O,xB3O,xB4O;
    float xC0O,xC1O,xC2O,xC3O,xC4O,xD0O,xD1O,xD2O,xD3O,xD4O;

    // row R feeds output I = R+2-DI; finalize I=R-2 inside iteration R.
    P_LOAD(E,0)
    P_LOAD(O,1) G_TAP(E,0,2) G_TAP(E,1,1) G_TAP(E,2,0)                              G_SH(E)
    P_LOAD(E,2) G_TAP(O,0,3) G_TAP(O,1,2) G_TAP(O,2,1) G_TAP(O,3,0)                 G_SH(O)
    P_LOAD(O,3) G_TAP(E,0,4) G_TAP(E,1,3) G_TAP(E,2,2) G_TAP(E,3,1) G_TAP(E,4,0) G_FIN(0) G_SH(E)
    P_LOAD(E,4) G_TAP(O,0,5) G_TAP(O,1,4) G_TAP(O,2,3) G_TAP(O,3,2) G_TAP(O,4,1) G_FIN(1) G_SH(O)
    P_LOAD(O,5) G_TAP(E,0,6) G_TAP(E,1,5) G_TAP(E,2,4) G_TAP(E,3,3) G_TAP(E,4,2) G_FIN(2) G_SH(E)
    P_LOAD(E,6) G_TAP(O,0,7) G_TAP(O,1,6) G_TAP(O,2,5) G_TAP(O,3,4) G_TAP(O,4,3) G_FIN(3) G_SH(O)
    P_LOAD(O,7) G_TAP(E,0,8) G_TAP(E,1,7) G_TAP(E,2,6) G_TAP(E,3,5) G_TAP(E,4,4) G_FIN(4) G_SH(E)
    P_LOAD(E,8) G_TAP(O,0,9) G_TAP(O,1,8) G_TAP(O,2,7) G_TAP(O,3,6) G_TAP(O,4,5) G_FIN(5) G_SH(O)
    P_LOAD(O,9) G_TAP(E,1,9) G_TAP(E,2,8) G_TAP(E,3,7) G_TAP(E,4,6)              G_FIN(6) G_SH(E)
                G_TAP(O,2,9) G_TAP(O,3,8) G_TAP(O,4,7)                           G_FIN(7) G_SH(O)
    // after final shift: cen2 = center(row 8), cen1 = center(row 9)
    G_FIN_(8, cen2A, cen2B, cen2C, cen2D)
    G_FIN_(9, cen1A, cen1B, cen1C, cen1D)

    // out[b][ch][j], b = bg*4 + k: base = bg*800 + k*200 + ch*100 + j
    float* ob = out + bg * 800 + j;
    ob[0]   = fA;  ob[100] = 0.01f * pA;
    ob[200] = fB;  ob[300] = 0.01f * pB;
    ob[400] = fC;  ob[500] = 0.01f * pC;
    ob[600] = fD;  ob[700] = 0.01f * pD;
}

extern "C" void kernel_launch(void* const* d_in, const int* in_sizes, int n_in,
                              void* d_out, int out_size, void* d_ws, size_t ws_size,
                              hipStream_t stream) {
    const float* x = (const float*)d_in[0];   // (16384, 10, 100) f32
    const float* w = (const float*)d_in[1];   // (10, 100, 5, 5)  f32
    float* out = (float*)d_out;               // (16384, 2, 100)  f32
    // threads = (16384/4 batches) * 100 j = 409600 -> 1600 blocks of 256
    dim3 grid(1600), block(256);
    hipLaunchKernelGGL(glm_fused, grid, block, 0, stream, x, w, out);
}